// Round 3
// baseline (127.008 us; speedup 1.0000x reference)
//
#include <hip/hip_runtime.h>

// Problem constants: B=4, C=32, H=W=256, heads=4, head_dim=8, amp=2.
#define Bdim 4
#define Cdim 32
#define NH   4
#define HD   8
#define Hdim 256
#define Wdim 256
#define AMP  2
#define KS   5

// R3: d-pair software pipeline (T14 issue-early/write-late). R2 showed kernel
// ~17.8us = T_mem(10.5) + T_comp(7) with ZERO overlap: every wave's compute was
// gated on the last of its 26 VMEM loads, which lands at the end of the global
// stream. Now: stage pair0; {load pair d+1 -> regs | compute pair d | pack+write
// pair d+1}. dot[5][5][2] accumulators (50 VGPR); exp/softmax once at the end.
// launch_bounds(256,4): cap 128 VGPR, 16 waves/CU, grid 2048 = 2x oversubscribed.
#define XT    32
#define TY    4
#define TROWS 8                     // TY + 2*AMP
#define TPOS  40
#define NPAIRS 16                   // 4 heads * 4 d-pairs
#define PAIR_STRIDE (TROWS * TPOS)  // 320
#define TILE_SLOTS (NPAIRS * PAIR_STRIDE)   // 5120 * 4B = 20 KB

typedef _Float16 h2 __attribute__((ext_vector_type(2)));

static __device__ __forceinline__ float dot2acc(h2 a, h2 b, float c) {
#if __has_builtin(__builtin_amdgcn_fdot2)
    return __builtin_amdgcn_fdot2(a, b, c, false);
#else
    return c + (float)a.x * (float)b.x + (float)a.y * (float)b.y;
#endif
}

__global__ __launch_bounds__(256, 4) void natt_offset_kernel(
    const float* __restrict__ xq,
    const float* __restrict__ xk,
    float* __restrict__ out)
{
    __shared__ __align__(16) float kt[TILE_SLOTS];

    const int tid = threadIdx.x;
    // XCD swizzle: bid%8 = XCD; contiguous 32-row y-slab (8 y-tiles) per XCD.
    const int bid = blockIdx.x;
    const int r8  = bid & 7;
    const int u   = bid >> 3;
    const int yt  = r8 * 8 + (u & 7);   // 0..63
    const int rst = u >> 3;
    const int xt  = rst & 7;            // 0..7
    const int b   = rst >> 3;           // 0..3

    const int Y0 = yt * TY;
    const int X0 = xt * XT;
    const bool interior = (yt != 0) && (yt != 63) && (xt != 0) && (xt != 7);

    const int h    = tid >> 6;          // wave = head
    const int lane = tid & 63;
    const int row  = lane >> 4;         // 0..3
    const int qx   = lane & 15;         // 0..15 (2 px each)
    const int y    = Y0 + row;
    const int x0   = X0 + qx * 2;

    const size_t plane = (size_t)Hdim * Wdim;
    const float scale = 0.35355339059327373f;   // 8^-0.5

    // ---- q loads FIRST: front of the VMEM queue, independent of staging.
    const float* qb = xq + (size_t)b * Cdim * plane + (size_t)y * Wdim + x0;
    h2 q2[4][2];
    #pragma unroll
    for (int d2 = 0; d2 < 4; ++d2) {
        const float2 qa = *(const float2*)(qb + (size_t)((2 * d2)     * NH + h) * plane);
        const float2 qc = *(const float2*)(qb + (size_t)((2 * d2 + 1) * NH + h) * plane);
        const float qa2[2] = {qa.x, qa.y};
        const float qc2[2] = {qc.x, qc.y};
        #pragma unroll
        for (int p = 0; p < 2; ++p) {
            q2[d2][p].x = (_Float16)(qa2[p] * scale);
            q2[d2][p].y = (_Float16)(qc2[p] * scale);
        }
    }

    const float* kb = xk + (size_t)b * Cdim * plane;

    // ---- per-pair staging geometry: 80 float4 jobs/wave = job `lane` for all,
    // job `64+lane` for lanes<16. Coordinates are d2-invariant: precompute once.
    const int c4_0 = lane % 10,        rw_0 = lane / 10;          // rows 0..6
    const int c4_1 = (64 + lane) % 10, rw_1 = (64 + lane) / 10;   // rows 6..7 (lane<16)
    int yr0 = Y0 - AMP + rw_0, yr1 = Y0 - AMP + rw_1;
    int xs0 = X0 - 6 + c4_0 * 4, xs1 = X0 - 6 + c4_1 * 4;
    int sh0 = 0, sh1 = 0;
    if (!interior) {
        yr0 = yr0 < 0 ? 0 : (yr0 > Hdim - 1 ? Hdim - 1 : yr0);
        yr1 = yr1 < 0 ? 0 : (yr1 > Hdim - 1 ? Hdim - 1 : yr1);
        int xc0 = xs0 < 0 ? 0 : (xs0 > Wdim - 4 ? Wdim - 4 : xs0);
        int xc1 = xs1 < 0 ? 0 : (xs1 > Wdim - 4 ? Wdim - 4 : xs1);
        sh0 = xs0 - xc0; xs0 = xc0;     // -6, -2, 0, +2; rotate-clamp in pack
        sh1 = xs1 - xc1; xs1 = xc1;
    }
    const size_t off0 = (size_t)yr0 * Wdim + xs0;
    const size_t off1 = (size_t)yr1 * Wdim + xs1;

    float4 A0, B0, A1, B1;              // in-flight staging regs (issue-early)

    auto stage_load = [&](int d2) {
        const float* pa = kb + (size_t)(8 * d2 + h) * plane + off0;
        A0 = *(const float4*)pa;
        B0 = *(const float4*)(pa + 4 * plane);
        if (lane < 16) {
            const float* pb = kb + (size_t)(8 * d2 + h) * plane + off1;
            A1 = *(const float4*)pb;
            B1 = *(const float4*)(pb + 4 * plane);
        }
    };
    // pack f32 pairs -> f16x2, rotate-clamp (identity when sh==0), write-late.
    auto stage_write = [&](int d2) {
        const int base = ((d2 << 2) | h) * PAIR_STRIDE;
        {
            const float a[4]  = {A0.x, A0.y, A0.z, A0.w};
            const float bb[4] = {B0.x, B0.y, B0.z, B0.w};
            float o[4];
            #pragma unroll
            for (int k2 = 0; k2 < 4; ++k2) {
                int idx = k2 + sh0; idx = idx < 0 ? 0 : (idx > 3 ? 3 : idx);
                h2 pk; pk.x = (_Float16)a[idx]; pk.y = (_Float16)bb[idx];
                o[k2] = __builtin_bit_cast(float, pk);
            }
            *(float4*)(kt + base + rw_0 * TPOS + c4_0 * 4) =
                make_float4(o[0], o[1], o[2], o[3]);
        }
        if (lane < 16) {
            const float a[4]  = {A1.x, A1.y, A1.z, A1.w};
            const float bb[4] = {B1.x, B1.y, B1.z, B1.w};
            float o[4];
            #pragma unroll
            for (int k2 = 0; k2 < 4; ++k2) {
                int idx = k2 + sh1; idx = idx < 0 ? 0 : (idx > 3 ? 3 : idx);
                h2 pk; pk.x = (_Float16)a[idx]; pk.y = (_Float16)bb[idx];
                o[k2] = __builtin_bit_cast(float, pk);
            }
            *(float4*)(kt + base + rw_1 * TPOS + c4_1 * 4) =
                make_float4(o[0], o[1], o[2], o[3]);
        }
    };

    float dot[KS][KS][2];
    #pragma unroll
    for (int r = 0; r < KS; ++r)
        #pragma unroll
        for (int dj = 0; dj < KS; ++dj) { dot[r][dj][0] = 0.f; dot[r][dj][1] = 0.f; }

    auto compute_pair = [&](int d2) {
        #pragma unroll
        for (int r = 0; r < KS; ++r) {
            // 6-pos window: pos qx*2+4 .. qx*2+9, three aligned b64s
            const float* wp = kt + ((d2 << 2) | h) * PAIR_STRIDE
                                 + (row + r) * TPOS + (qx * 2 + 4);
            const float2 wa = *(const float2*)wp;
            const float2 wb = *(const float2*)(wp + 2);
            const float2 wc = *(const float2*)(wp + 4);
            const float wf[6] = {wa.x, wa.y, wb.x, wb.y, wc.x, wc.y};
            h2 w[6];
            #pragma unroll
            for (int k2 = 0; k2 < 6; ++k2) w[k2] = __builtin_bit_cast(h2, wf[k2]);
            #pragma unroll
            for (int dj = 0; dj < KS; ++dj) {
                #pragma unroll
                for (int p = 0; p < 2; ++p)
                    dot[r][dj][p] = dot2acc(q2[d2][p], w[p + dj], dot[r][dj][p]);
            }
        }
    };

    // ---- software pipeline: loads of pair d+1 fly under compute of pair d.
    // NO barrier anywhere: wave h writes/reads only its own pairs ((d2<<2)|h).
    stage_load(0);
    stage_write(0);
    stage_load(1);
    compute_pair(0);
    stage_write(1);
    stage_load(2);
    compute_pair(1);
    stage_write(2);
    stage_load(3);
    compute_pair(2);
    stage_write(3);
    compute_pair(3);

    // ---- exp / softmax-weighted offset accumulation (reads dot[][][])
    float Z[2]  = {0.f, 0.f};
    float sx[2] = {0.f, 0.f};
    float sy[2] = {0.f, 0.f};

    #pragma unroll
    for (int r = 0; r < KS; ++r) {
        const float fdi = (float)(r - AMP);
        if (interior) {                        // block-uniform: no masks
            #pragma unroll
            for (int p = 0; p < 2; ++p) {
                float e[KS];
                #pragma unroll
                for (int dj = 0; dj < KS; ++dj) e[dj] = __expf(dot[r][dj][p]);
                const float er = ((e[0] + e[1]) + (e[2] + e[3])) + e[4];
                Z[p]  += er;
                sx[p] += fdi * er;
                sy[p] += (e[3] - e[1]) + 2.f * (e[4] - e[0]);
            }
        } else {
            const int yy = y + r - AMP;
            const bool rowok = (yy >= 0) && (yy < Hdim);
            #pragma unroll
            for (int p = 0; p < 2; ++p) {
                float e[KS];
                #pragma unroll
                for (int dj = 0; dj < KS; ++dj) {
                    const int xx = x0 + p + dj - AMP;
                    const bool ok = rowok && (xx >= 0) && (xx < Wdim);
                    e[dj] = ok ? __expf(dot[r][dj][p]) : 0.f;
                }
                const float er = ((e[0] + e[1]) + (e[2] + e[3])) + e[4];
                Z[p]  += er;
                sx[p] += fdi * er;
                sy[p] += (e[3] - e[1]) + 2.f * (e[4] - e[0]);
            }
        }
    }

    // ---- head mean through LDS (reuse kt; barrier before and after red writes).
    __syncthreads();
    float* red = kt;                     // 4 heads x 2 ch x 128 px = 1024 floats
    const int pxl = row * XT + qx * 2;
    {
        const float i0 = 1.f / Z[0], i1 = 1.f / Z[1];
        *(float2*)(red + (h * 2 + 0) * (XT * TY) + pxl) =
            make_float2(sx[0]*i0, sx[1]*i1);
        *(float2*)(red + (h * 2 + 1) * (XT * TY) + pxl) =
            make_float2(sy[0]*i0, sy[1]*i1);
    }
    __syncthreads();

    if (h < 2) {                         // ch 0 = row-offset (di), 1 = col-offset (dj)
        float acc[2] = {0.f, 0.f};
        #pragma unroll
        for (int hh = 0; hh < NH; ++hh) {
            const float2 v = *(const float2*)(red + (hh * 2 + h) * (XT * TY) + pxl);
            acc[0] += v.x; acc[1] += v.y;
        }
        *(float2*)(out + ((size_t)b * 2 + h) * plane + (size_t)y * Wdim + x0) =
            make_float2(acc[0]*0.25f, acc[1]*0.25f);
    }
}

extern "C" void kernel_launch(void* const* d_in, const int* in_sizes, int n_in,
                              void* d_out, int out_size, void* d_ws, size_t ws_size,
                              hipStream_t stream) {
    const float* xq = (const float*)d_in[0];
    const float* xk = (const float*)d_in[1];
    float* out = (float*)d_out;

    // 64 y-tiles x 8 x-tiles x 4 batches = 2048 blocks
    natt_offset_kernel<<<dim3(2048, 1, 1), dim3(256, 1, 1), 0, stream>>>(xq, xk, out);
}

// Round 5
// 112.477 us; speedup vs baseline: 1.1292x; 1.1292x over previous
//
#include <hip/hip_runtime.h>

// Problem constants: B=4, C=32, H=W=256, heads=4, head_dim=8, amp=2.
#define Bdim 4
#define Cdim 32
#define NH   4
#define HD   8
#define Hdim 256
#define Wdim 256
#define AMP  2
#define KS   5

// R4: R3's d-pair pipeline, de-spilled. R3 failed (51us, VGPR=64, WRITE 54MB)
// because stage_write used runtime-indexed float arrays (a[k2+sh]) on EVERY
// path -> scratch (rule #20), plus launch_bounds(256,4) anchored 64 regs.
// Fix: interior blocks get a static pack (no rotate); boundary blocks use a
// static-index select chain (sh in {-6,-2,0,+2} -> ?: over static indices).
// No min-waves bound: let allocator hold dot[5][5][2] (50 regs) in VGPRs.
#define XT    32
#define TY    4
#define TROWS 8                     // TY + 2*AMP
#define TPOS  40
#define NPAIRS 16                   // 4 heads * 4 d-pairs
#define PAIR_STRIDE (TROWS * TPOS)  // 320
#define TILE_SLOTS (NPAIRS * PAIR_STRIDE)   // 5120 * 4B = 20 KB

typedef _Float16 h2 __attribute__((ext_vector_type(2)));

static __device__ __forceinline__ float dot2acc(h2 a, h2 b, float c) {
#if __has_builtin(__builtin_amdgcn_fdot2)
    return __builtin_amdgcn_fdot2(a, b, c, false);
#else
    return c + (float)a.x * (float)b.x + (float)a.y * (float)b.y;
#endif
}

__global__ __launch_bounds__(256) void natt_offset_kernel(
    const float* __restrict__ xq,
    const float* __restrict__ xk,
    float* __restrict__ out)
{
    __shared__ __align__(16) float kt[TILE_SLOTS];

    const int tid = threadIdx.x;
    // XCD swizzle: bid%8 = XCD; contiguous 32-row y-slab (8 y-tiles) per XCD.
    const int bid = blockIdx.x;
    const int r8  = bid & 7;
    const int u   = bid >> 3;
    const int yt  = r8 * 8 + (u & 7);   // 0..63
    const int rst = u >> 3;
    const int xt  = rst & 7;            // 0..7
    const int b   = rst >> 3;           // 0..3

    const int Y0 = yt * TY;
    const int X0 = xt * XT;
    const bool interior = (yt != 0) && (yt != 63) && (xt != 0) && (xt != 7);

    const int h    = tid >> 6;          // wave = head
    const int lane = tid & 63;
    const int row  = lane >> 4;         // 0..3
    const int qx   = lane & 15;         // 0..15 (2 px each)
    const int y    = Y0 + row;
    const int x0   = X0 + qx * 2;

    const size_t plane = (size_t)Hdim * Wdim;
    const float scale = 0.35355339059327373f;   // 8^-0.5

    // ---- q loads FIRST: front of the VMEM queue, independent of staging.
    const float* qb = xq + (size_t)b * Cdim * plane + (size_t)y * Wdim + x0;
    h2 q2[4][2];
    #pragma unroll
    for (int d2 = 0; d2 < 4; ++d2) {
        const float2 qa = *(const float2*)(qb + (size_t)((2 * d2)     * NH + h) * plane);
        const float2 qc = *(const float2*)(qb + (size_t)((2 * d2 + 1) * NH + h) * plane);
        const float qa2[2] = {qa.x, qa.y};
        const float qc2[2] = {qc.x, qc.y};
        #pragma unroll
        for (int p = 0; p < 2; ++p) {
            q2[d2][p].x = (_Float16)(qa2[p] * scale);
            q2[d2][p].y = (_Float16)(qc2[p] * scale);
        }
    }

    const float* kb = xk + (size_t)b * Cdim * plane;

    // ---- per-pair staging geometry: 80 float4 jobs/wave = job `lane` for all,
    // job `64+lane` for lanes<16. Coordinates are d2-invariant: precompute once.
    const int c4_0 = lane % 10,        rw_0 = lane / 10;          // rows 0..6
    const int c4_1 = (64 + lane) % 10, rw_1 = (64 + lane) / 10;   // rows 6..7 (lane<16)
    int yr0 = Y0 - AMP + rw_0, yr1 = Y0 - AMP + rw_1;
    int xs0 = X0 - 6 + c4_0 * 4, xs1 = X0 - 6 + c4_1 * 4;
    int sh0 = 0, sh1 = 0;
    if (!interior) {
        yr0 = yr0 < 0 ? 0 : (yr0 > Hdim - 1 ? Hdim - 1 : yr0);
        yr1 = yr1 < 0 ? 0 : (yr1 > Hdim - 1 ? Hdim - 1 : yr1);
        int xc0 = xs0 < 0 ? 0 : (xs0 > Wdim - 4 ? Wdim - 4 : xs0);
        int xc1 = xs1 < 0 ? 0 : (xs1 > Wdim - 4 ? Wdim - 4 : xs1);
        sh0 = xs0 - xc0; xs0 = xc0;     // -6, -2, 0, +2; rotate-clamp in pack
        sh1 = xs1 - xc1; xs1 = xc1;
    }
    const size_t off0 = (size_t)yr0 * Wdim + xs0;
    const size_t off1 = (size_t)yr1 * Wdim + xs1;

    float4 A0, B0, A1, B1;              // in-flight staging regs (issue-early)

    auto stage_load = [&](int d2) {
        const float* pa = kb + (size_t)(8 * d2 + h) * plane + off0;
        A0 = *(const float4*)pa;
        B0 = *(const float4*)(pa + 4 * plane);
        if (lane < 16) {
            const float* pb = kb + (size_t)(8 * d2 + h) * plane + off1;
            A1 = *(const float4*)pb;
            B1 = *(const float4*)(pb + 4 * plane);
        }
    };

    // interior pack: straight f32 pair -> f16x2, ALL indices static.
    auto stage_write_fast = [&](int d2) {
        const int base = ((d2 << 2) | h) * PAIR_STRIDE;
        {
            const float a[4]  = {A0.x, A0.y, A0.z, A0.w};
            const float bb[4] = {B0.x, B0.y, B0.z, B0.w};
            float o[4];
            #pragma unroll
            for (int k2 = 0; k2 < 4; ++k2) {
                h2 pk; pk.x = (_Float16)a[k2]; pk.y = (_Float16)bb[k2];
                o[k2] = __builtin_bit_cast(float, pk);
            }
            *(float4*)(kt + base + rw_0 * TPOS + c4_0 * 4) =
                make_float4(o[0], o[1], o[2], o[3]);
        }
        if (lane < 16) {
            const float a[4]  = {A1.x, A1.y, A1.z, A1.w};
            const float bb[4] = {B1.x, B1.y, B1.z, B1.w};
            float o[4];
            #pragma unroll
            for (int k2 = 0; k2 < 4; ++k2) {
                h2 pk; pk.x = (_Float16)a[k2]; pk.y = (_Float16)bb[k2];
                o[k2] = __builtin_bit_cast(float, pk);
            }
            *(float4*)(kt + base + rw_1 * TPOS + c4_1 * 4) =
                make_float4(o[0], o[1], o[2], o[3]);
        }
    };

    // boundary pack: rotate-clamp via STATIC-index select chain (sh is one of
    // {-6,-2,0,+2}); no runtime array indexing -> no scratch (R3 post-mortem).
    auto stage_write_rot = [&](int d2) {
        const int base = ((d2 << 2) | h) * PAIR_STRIDE;
        {
            const float a[4]  = {A0.x, A0.y, A0.z, A0.w};
            const float bb[4] = {B0.x, B0.y, B0.z, B0.w};
            float o[4];
            #pragma unroll
            for (int k2 = 0; k2 < 4; ++k2) {
                const int ip2 = (k2 + 2 > 3) ? 3 : k2 + 2;
                const int im2 = (k2 - 2 < 0) ? 0 : k2 - 2;
                const float fa = sh0 == 0 ? a[k2]
                               : (sh0 == 2 ? a[ip2] : (sh0 == -2 ? a[im2] : a[0]));
                const float fb = sh0 == 0 ? bb[k2]
                               : (sh0 == 2 ? bb[ip2] : (sh0 == -2 ? bb[im2] : bb[0]));
                h2 pk; pk.x = (_Float16)fa; pk.y = (_Float16)fb;
                o[k2] = __builtin_bit_cast(float, pk);
            }
            *(float4*)(kt + base + rw_0 * TPOS + c4_0 * 4) =
                make_float4(o[0], o[1], o[2], o[3]);
        }
        if (lane < 16) {
            const float a[4]  = {A1.x, A1.y, A1.z, A1.w};
            const float bb[4] = {B1.x, B1.y, B1.z, B1.w};
            float o[4];
            #pragma unroll
            for (int k2 = 0; k2 < 4; ++k2) {
                const int ip2 = (k2 + 2 > 3) ? 3 : k2 + 2;
                const int im2 = (k2 - 2 < 0) ? 0 : k2 - 2;
                const float fa = sh1 == 0 ? a[k2]
                               : (sh1 == 2 ? a[ip2] : (sh1 == -2 ? a[im2] : a[0]));
                const float fb = sh1 == 0 ? bb[k2]
                               : (sh1 == 2 ? bb[ip2] : (sh1 == -2 ? bb[im2] : bb[0]));
                h2 pk; pk.x = (_Float16)fa; pk.y = (_Float16)fb;
                o[k2] = __builtin_bit_cast(float, pk);
            }
            *(float4*)(kt + base + rw_1 * TPOS + c4_1 * 4) =
                make_float4(o[0], o[1], o[2], o[3]);
        }
    };

    float dot[KS][KS][2];
    #pragma unroll
    for (int r = 0; r < KS; ++r)
        #pragma unroll
        for (int dj = 0; dj < KS; ++dj) { dot[r][dj][0] = 0.f; dot[r][dj][1] = 0.f; }

    auto compute_pair = [&](int d2) {
        #pragma unroll
        for (int r = 0; r < KS; ++r) {
            // 6-pos window: pos qx*2+4 .. qx*2+9, three aligned b64s
            const float* wp = kt + ((d2 << 2) | h) * PAIR_STRIDE
                                 + (row + r) * TPOS + (qx * 2 + 4);
            const float2 wa = *(const float2*)wp;
            const float2 wb = *(const float2*)(wp + 2);
            const float2 wc = *(const float2*)(wp + 4);
            const float wf[6] = {wa.x, wa.y, wb.x, wb.y, wc.x, wc.y};
            h2 w[6];
            #pragma unroll
            for (int k2 = 0; k2 < 6; ++k2) w[k2] = __builtin_bit_cast(h2, wf[k2]);
            #pragma unroll
            for (int dj = 0; dj < KS; ++dj) {
                #pragma unroll
                for (int p = 0; p < 2; ++p)
                    dot[r][dj][p] = dot2acc(q2[d2][p], w[p + dj], dot[r][dj][p]);
            }
        }
    };

    // ---- software pipeline: loads of pair d+1 fly under compute of pair d.
    // NO barrier anywhere: wave h writes/reads only its own pairs ((d2<<2)|h).
    if (interior) {
        stage_load(0); stage_write_fast(0);
        stage_load(1); compute_pair(0); stage_write_fast(1);
        stage_load(2); compute_pair(1); stage_write_fast(2);
        stage_load(3); compute_pair(2); stage_write_fast(3);
        compute_pair(3);
    } else {
        stage_load(0); stage_write_rot(0);
        stage_load(1); compute_pair(0); stage_write_rot(1);
        stage_load(2); compute_pair(1); stage_write_rot(2);
        stage_load(3); compute_pair(2); stage_write_rot(3);
        compute_pair(3);
    }

    // ---- exp / softmax-weighted offset accumulation (reads dot[][][])
    float Z[2]  = {0.f, 0.f};
    float sx[2] = {0.f, 0.f};
    float sy[2] = {0.f, 0.f};

    #pragma unroll
    for (int r = 0; r < KS; ++r) {
        const float fdi = (float)(r - AMP);
        if (interior) {                        // block-uniform: no masks
            #pragma unroll
            for (int p = 0; p < 2; ++p) {
                float e[KS];
                #pragma unroll
                for (int dj = 0; dj < KS; ++dj) e[dj] = __expf(dot[r][dj][p]);
                const float er = ((e[0] + e[1]) + (e[2] + e[3])) + e[4];
                Z[p]  += er;
                sx[p] += fdi * er;
                sy[p] += (e[3] - e[1]) + 2.f * (e[4] - e[0]);
            }
        } else {
            const int yy = y + r - AMP;
            const bool rowok = (yy >= 0) && (yy < Hdim);
            #pragma unroll
            for (int p = 0; p < 2; ++p) {
                float e[KS];
                #pragma unroll
                for (int dj = 0; dj < KS; ++dj) {
                    const int xx = x0 + p + dj - AMP;
                    const bool ok = rowok && (xx >= 0) && (xx < Wdim);
                    e[dj] = ok ? __expf(dot[r][dj][p]) : 0.f;
                }
                const float er = ((e[0] + e[1]) + (e[2] + e[3])) + e[4];
                Z[p]  += er;
                sx[p] += fdi * er;
                sy[p] += (e[3] - e[1]) + 2.f * (e[4] - e[0]);
            }
        }
    }

    // ---- head mean through LDS (reuse kt; barrier before and after red writes).
    __syncthreads();
    float* red = kt;                     // 4 heads x 2 ch x 128 px = 1024 floats
    const int pxl = row * XT + qx * 2;
    {
        const float i0 = 1.f / Z[0], i1 = 1.f / Z[1];
        *(float2*)(red + (h * 2 + 0) * (XT * TY) + pxl) =
            make_float2(sx[0]*i0, sx[1]*i1);
        *(float2*)(red + (h * 2 + 1) * (XT * TY) + pxl) =
            make_float2(sy[0]*i0, sy[1]*i1);
    }
    __syncthreads();

    if (h < 2) {                         // ch 0 = row-offset (di), 1 = col-offset (dj)
        float acc[2] = {0.f, 0.f};
        #pragma unroll
        for (int hh = 0; hh < NH; ++hh) {
            const float2 v = *(const float2*)(red + (hh * 2 + h) * (XT * TY) + pxl);
            acc[0] += v.x; acc[1] += v.y;
        }
        *(float2*)(out + ((size_t)b * 2 + h) * plane + (size_t)y * Wdim + x0) =
            make_float2(acc[0]*0.25f, acc[1]*0.25f);
    }
}

extern "C" void kernel_launch(void* const* d_in, const int* in_sizes, int n_in,
                              void* d_out, int out_size, void* d_ws, size_t ws_size,
                              hipStream_t stream) {
    const float* xq = (const float*)d_in[0];
    const float* xk = (const float*)d_in[1];
    float* out = (float*)d_out;

    // 64 y-tiles x 8 x-tiles x 4 batches = 2048 blocks
    natt_offset_kernel<<<dim3(2048, 1, 1), dim3(256, 1, 1), 0, stream>>>(xq, xk, out);
}

// Round 6
// 100.518 us; speedup vs baseline: 1.2635x; 1.1190x over previous
//
#include <hip/hip_runtime.h>

// Problem constants: B=4, C=32, H=W=256, heads=4, head_dim=8, amp=2.
#define Bdim 4
#define Cdim 32
#define NH   4
#define HD   8
#define Hdim 256
#define Wdim 256
#define AMP  2
#define KS   5

// R6: revert to R2's flat structure (manual d-pair pipeline was 2x WORSE:
// serialized loads killed MLP; R3=51us spill, R4/5=30us). Attack the real
// limiter instead: VMEM request bytes. R2 @TY=4 requested ~117MB (k halo amp
// 2.0y x 1.25x); at the ~6.1TB/s load path that is ~19us ~= measured 17.8.
// Now TY=8 (halo amp 1.875x total, ~96MB) with 512-thread blocks so occupancy
// stays full: 1024 blocks x 8 waves = 4 blocks/CU x 30KB LDS = 32 waves/CU.
// Staging is block-cooperative (one barrier); compute identical to R2 with
// two waves per head (wave w: head w&3, row-half w>>2).
#define XT    32
#define TY    8
#define TROWS 12                    // TY + 2*AMP
#define TPOS  40
#define NPAIRS 16                   // 4 heads * 4 d-pairs
#define PAIR_STRIDE (TROWS * TPOS)  // 480
#define TILE_SLOTS (NPAIRS * PAIR_STRIDE)   // 7680 * 4B = 30 KB
#define NJOBS (NPAIRS * TROWS * 10) // 1920 float4 staging jobs

typedef _Float16 h2 __attribute__((ext_vector_type(2)));

static __device__ __forceinline__ float dot2acc(h2 a, h2 b, float c) {
#if __has_builtin(__builtin_amdgcn_fdot2)
    return __builtin_amdgcn_fdot2(a, b, c, false);
#else
    return c + (float)a.x * (float)b.x + (float)a.y * (float)b.y;
#endif
}

__global__ __launch_bounds__(512) void natt_offset_kernel(
    const float* __restrict__ xq,
    const float* __restrict__ xk,
    float* __restrict__ out)
{
    __shared__ __align__(16) float kt[TILE_SLOTS];

    const int tid = threadIdx.x;
    // XCD swizzle: bid&7 = XCD; contiguous 64-row y-slab (8 y-tiles) per XCD.
    const int bid = blockIdx.x;
    const int r8  = bid & 7;
    const int u   = bid >> 3;
    const int yt  = r8 * 4 + (u & 3);   // 0..31
    const int rst = u >> 2;
    const int xt  = rst & 7;            // 0..7
    const int b   = rst >> 3;           // 0..3

    const int Y0 = yt * TY;
    const int X0 = xt * XT;
    const bool interior = (yt != 0) && (yt != 31) && (xt != 0) && (xt != 7);

    const int w    = tid >> 6;          // wave 0..7
    const int h    = w & 3;             // head
    const int wrb  = (w >> 2) * 4;      // row-half base: 0 or 4
    const int lane = tid & 63;
    const int row  = lane >> 4;         // 0..3
    const int qx   = lane & 15;         // 0..15 (2 px each)
    const int y    = Y0 + wrb + row;
    const int x0   = X0 + qx * 2;

    const size_t plane = (size_t)Hdim * Wdim;
    const float scale = 0.35355339059327373f;   // 8^-0.5

    // ---- block-cooperative staging: 1920 float4 jobs over 512 threads.
    // Job j: c4=j%10 (x-chunk), t=j/10: rw=t%12 (tile row), p=t/12 (pair).
    // Pair p = 4*d2+h -> channels 8*d2+h (A) and +4 (B). LDS f16x2 packed.
    {
        const float* kb = xk + (size_t)b * Cdim * plane;
        if (interior) {
            #pragma unroll
            for (int it = 0; it < 4; ++it) {
                const int j = tid + it * 512;
                if (j < NJOBS) {
                    const int c4 = j % 10;
                    const int t  = j / 10;
                    const int rw = t % TROWS;
                    const int p  = t / TROWS;            // pair 0..15
                    const int c0 = 8 * (p >> 2) + (p & 3);
                    const int yr = Y0 - AMP + rw;        // 6..249: no clamp
                    const int xs = X0 - 6 + c4 * 4;      // 26..222: no clamp
                    const float* pa = kb + (size_t)c0 * plane + (size_t)yr * Wdim + xs;
                    const float4 va = *(const float4*)pa;
                    const float4 vb = *(const float4*)(pa + 4 * plane);
                    const float a[4]  = {va.x, va.y, va.z, va.w};
                    const float bb[4] = {vb.x, vb.y, vb.z, vb.w};
                    float o[4];
                    #pragma unroll
                    for (int k2 = 0; k2 < 4; ++k2) {
                        h2 pk;
                        pk.x = (_Float16)a[k2];
                        pk.y = (_Float16)bb[k2];
                        o[k2] = __builtin_bit_cast(float, pk);
                    }
                    *(float4*)(kt + p * PAIR_STRIDE + rw * TPOS + c4 * 4) =
                        make_float4(o[0], o[1], o[2], o[3]);
                }
            }
        } else {
            // clamped loads + STATIC-index rotate (sh in {-6,-2,0,+2}; R3
            // post-mortem: runtime-indexed arrays spill to scratch).
            #pragma unroll
            for (int it = 0; it < 4; ++it) {
                const int j = tid + it * 512;
                if (j < NJOBS) {
                    const int c4 = j % 10;
                    const int t  = j / 10;
                    const int rw = t % TROWS;
                    const int p  = t / TROWS;
                    const int c0 = 8 * (p >> 2) + (p & 3);
                    int yr = Y0 - AMP + rw;
                    yr = yr < 0 ? 0 : (yr > Hdim - 1 ? Hdim - 1 : yr);
                    const int xs = X0 - 6 + c4 * 4;
                    const int xc = xs < 0 ? 0 : (xs > Wdim - 4 ? Wdim - 4 : xs);
                    const int sh = xs - xc;              // -6, -2, 0, +2
                    const float* pa = kb + (size_t)c0 * plane + (size_t)yr * Wdim + xc;
                    const float4 va = *(const float4*)pa;
                    const float4 vb = *(const float4*)(pa + 4 * plane);
                    const float a[4]  = {va.x, va.y, va.z, va.w};
                    const float bb[4] = {vb.x, vb.y, vb.z, vb.w};
                    float o[4];
                    #pragma unroll
                    for (int k2 = 0; k2 < 4; ++k2) {
                        const int ip2 = (k2 + 2 > 3) ? 3 : k2 + 2;
                        const int im2 = (k2 - 2 < 0) ? 0 : k2 - 2;
                        const float fa = sh == 0 ? a[k2]
                                       : (sh == 2 ? a[ip2] : (sh == -2 ? a[im2] : a[0]));
                        const float fb = sh == 0 ? bb[k2]
                                       : (sh == 2 ? bb[ip2] : (sh == -2 ? bb[im2] : bb[0]));
                        h2 pk; pk.x = (_Float16)fa; pk.y = (_Float16)fb;
                        o[k2] = __builtin_bit_cast(float, pk);
                    }
                    *(float4*)(kt + p * PAIR_STRIDE + rw * TPOS + c4 * 4) =
                        make_float4(o[0], o[1], o[2], o[3]);
                }
            }
        }
    }

    // ---- q fragments for this head/row-half, packed f16x2 by d-pair, 2 px each
    const float* qb = xq + (size_t)b * Cdim * plane + (size_t)y * Wdim + x0;
    h2 q2[4][2];
    #pragma unroll
    for (int d2 = 0; d2 < 4; ++d2) {
        const float2 qa = *(const float2*)(qb + (size_t)((2 * d2)     * NH + h) * plane);
        const float2 qc = *(const float2*)(qb + (size_t)((2 * d2 + 1) * NH + h) * plane);
        const float qa2[2] = {qa.x, qa.y};
        const float qc2[2] = {qc.x, qc.y};
        #pragma unroll
        for (int p = 0; p < 2; ++p) {
            q2[d2][p].x = (_Float16)(qa2[p] * scale);
            q2[d2][p].y = (_Float16)(qc2[p] * scale);
        }
    }

    // staging is cross-wave now (waves w and w+4 share head pairs): barrier.
    __syncthreads();

    float Z[2]  = {0.f, 0.f};
    float sx[2] = {0.f, 0.f};
    float sy[2] = {0.f, 0.f};

    #pragma unroll
    for (int r = 0; r < KS; ++r) {
        float dot[KS][2];
        #pragma unroll
        for (int dj = 0; dj < KS; ++dj) { dot[dj][0] = 0.f; dot[dj][1] = 0.f; }

        #pragma unroll
        for (int d2 = 0; d2 < 4; ++d2) {
            // 6-pos window: pos qx*2+4 .. qx*2+9, three aligned b64s
            const float* wp = kt + ((d2 << 2) | h) * PAIR_STRIDE
                                 + (wrb + row + r) * TPOS + (qx * 2 + 4);
            const float2 wa = *(const float2*)wp;
            const float2 wb = *(const float2*)(wp + 2);
            const float2 wc = *(const float2*)(wp + 4);
            const float wf[6] = {wa.x, wa.y, wb.x, wb.y, wc.x, wc.y};
            h2 wreg[6];
            #pragma unroll
            for (int k2 = 0; k2 < 6; ++k2) wreg[k2] = __builtin_bit_cast(h2, wf[k2]);
            #pragma unroll
            for (int dj = 0; dj < KS; ++dj) {
                #pragma unroll
                for (int p = 0; p < 2; ++p)
                    dot[dj][p] = dot2acc(q2[d2][p], wreg[p + dj], dot[dj][p]);
            }
        }

        const float fdi = (float)(r - AMP);
        if (interior) {                        // block-uniform: no masks
            #pragma unroll
            for (int p = 0; p < 2; ++p) {
                float e[KS];
                #pragma unroll
                for (int dj = 0; dj < KS; ++dj) e[dj] = __expf(dot[dj][p]);
                const float er = ((e[0] + e[1]) + (e[2] + e[3])) + e[4];
                Z[p]  += er;
                sx[p] += fdi * er;
                sy[p] += (e[3] - e[1]) + 2.f * (e[4] - e[0]);
            }
        } else {
            const int yy = y + r - AMP;
            const bool rowok = (yy >= 0) && (yy < Hdim);
            #pragma unroll
            for (int p = 0; p < 2; ++p) {
                float e[KS];
                #pragma unroll
                for (int dj = 0; dj < KS; ++dj) {
                    const int xx = x0 + p + dj - AMP;
                    const bool ok = rowok && (xx >= 0) && (xx < Wdim);
                    e[dj] = ok ? __expf(dot[dj][p]) : 0.f;
                }
                const float er = ((e[0] + e[1]) + (e[2] + e[3])) + e[4];
                Z[p]  += er;
                sx[p] += fdi * er;
                sy[p] += (e[3] - e[1]) + 2.f * (e[4] - e[0]);
            }
        }
    }

    // ---- head mean through LDS (reuse kt; barrier before and after red writes).
    __syncthreads();
    float* red = kt;                     // 4 heads x 2 ch x 256 px = 2048 floats
    const int pxl = (wrb + row) * XT + qx * 2;
    {
        const float i0 = 1.f / Z[0], i1 = 1.f / Z[1];
        *(float2*)(red + (h * 2 + 0) * (XT * TY) + pxl) =
            make_float2(sx[0]*i0, sx[1]*i1);
        *(float2*)(red + (h * 2 + 1) * (XT * TY) + pxl) =
            make_float2(sy[0]*i0, sy[1]*i1);
    }
    __syncthreads();

    if (w < 4) {                         // wave w: ch=w&1, row-half=(w>>1)*4
        const int ch  = w & 1;
        const int rr  = (w >> 1) * 4 + row;
        const int px2 = rr * XT + qx * 2;
        float acc[2] = {0.f, 0.f};
        #pragma unroll
        for (int hh = 0; hh < NH; ++hh) {
            const float2 v = *(const float2*)(red + (hh * 2 + ch) * (XT * TY) + px2);
            acc[0] += v.x; acc[1] += v.y;
        }
        *(float2*)(out + ((size_t)b * 2 + ch) * plane + (size_t)(Y0 + rr) * Wdim + x0) =
            make_float2(acc[0]*0.25f, acc[1]*0.25f);
    }
}

extern "C" void kernel_launch(void* const* d_in, const int* in_sizes, int n_in,
                              void* d_out, int out_size, void* d_ws, size_t ws_size,
                              hipStream_t stream) {
    const float* xq = (const float*)d_in[0];
    const float* xk = (const float*)d_in[1];
    float* out = (float*)d_out;

    // 32 y-tiles x 8 x-tiles x 4 batches = 1024 blocks x 512 threads
    natt_offset_kernel<<<dim3(1024, 1, 1), dim3(512, 1, 1), 0, stream>>>(xq, xk, out);
}